// Round 6
// baseline (1789.582 us; speedup 1.0000x reference)
//
#include <hip/hip_runtime.h>
#include <hip/hip_bf16.h>

#define Bb    32
#define Nn_   2048
#define DESCn 16
#define Hn    64
#define Pn    80
#define KM    5

#define XSTRIDE ((size_t)Bb * Pn * Nn_)   // elements per diffusion buffer (2560*2048)

typedef __attribute__((ext_vector_type(8))) short bf16x8;
typedef __attribute__((ext_vector_type(4))) short s16x4;
typedef __attribute__((ext_vector_type(4))) float f32x4;

__device__ __forceinline__ short f2bf(float f) {
    unsigned u = __builtin_bit_cast(unsigned, f);
    u = u + 0x7FFFu + ((u >> 16) & 1u);
    return (short)(u >> 16);
}
__device__ __forceinline__ float bf2f(short s) {
    unsigned u = ((unsigned)(unsigned short)s) << 16;
    return __builtin_bit_cast(float, u);
}

__device__ __forceinline__ void glds16(const void* g, void* l) {
    __builtin_amdgcn_global_load_lds((const __attribute__((address_space(1))) void*)g,
                                     (__attribute__((address_space(3))) void*)l, 16, 0, 0);
}

// Packed fragment layout for B-operands (and packed-A staging):
//   matrix element (r, c), r = row (the B "m" index), c = col (the k index).
//   block = (mt=r>>8, t=c>>6, rb=(r>>4)&15, ks=(c>>5)&1): 512 shorts (1 KB).
//   interior: g=(c>>3)&3, l16=r&15, e=c&7 -> g*128 + l16*8 + e.
//   One wave fragment read = block base + lane*8 shorts: lane (g=l>>4,l16=l&15)
//   gets rows rb*16+l16, k-group ks*32+g*8 -- exactly the MFMA B fragment, as
//   64 contiguous 16B lane-chunks (perfectly coalesced dwordx4).
__device__ __forceinline__ size_t poff(int r, int c) {
    return ((((size_t)(r >> 8) * 32 + (c >> 6)) * 16 + ((r >> 4) & 15)) * 2 + ((c >> 5) & 1)) * 512
           + (size_t)(((c >> 3) & 3) * 128 + (r & 15) * 8 + (c & 7));
}

// ---------------- support construction ----------------

// one pass over adj: per-64x64-tile row sums and col sums, atomically accumulated
__global__ void sums_kernel(const float* __restrict__ adj, float* __restrict__ rsum,
                            float* __restrict__ csum) {
    __shared__ float tile[64][65];
    const int r0 = blockIdx.y * 64, c0 = blockIdx.x * 64;
    const int t = threadIdx.x;
    for (int i = t; i < 64 * 64; i += 256)
        tile[i >> 6][i & 63] = adj[(size_t)(r0 + (i >> 6)) * Nn_ + c0 + (i & 63)];
    __syncthreads();
    if (t < 64) {
        float s = 0.f;
#pragma unroll 8
        for (int j = 0; j < 64; ++j) s += tile[t][j];
        atomicAdd(&rsum[r0 + t], s);
    } else if (t < 128) {
        int c = t - 64;
        float s = 0.f;
#pragma unroll 8
        for (int j = 0; j < 64; ++j) s += tile[j][c];
        atomicAdd(&csum[c0 + c], s);
    }
}

__global__ void inv2_kernel(const float* __restrict__ rs, const float* __restrict__ cs,
                            float* __restrict__ ri, float* __restrict__ ci) {
    int i = blockIdx.x * 256 + threadIdx.x;
    if (i < Nn_) {
        ri[i] = rs[i] > 0.f ? 1.f / rs[i] : 0.f;
        ci[i] = cs[i] > 0.f ? 1.f / cs[i] : 0.f;
    }
}

// All four supports written in PACKED layout (poff):
//   S1 [i][j] = adj[i][j] * cinv[j]
//   S0T[i][j] = adj[i][j] * rinv[i]     (= S0^T)
//   S0 [i][j] = adj[j][i] * rinv[j]
//   S1T[i][j] = adj[j][i] * cinv[i]     (= S1^T)
__global__ void build_S_kernel(const float* __restrict__ adj, const float* __restrict__ rinv,
                               const float* __restrict__ cinv, short* __restrict__ S0p,
                               short* __restrict__ S1p, short* __restrict__ S0Tp,
                               short* __restrict__ S1Tp) {
    __shared__ float tileT[64][65];   // tileT[a][b] = adj[c0+a][r0+b]
    const int r0 = blockIdx.y * 64, c0 = blockIdx.x * 64;
    const int t = threadIdx.x;
    for (int i = t; i < 64 * 64; i += 256) {
        int a = i >> 6, b = i & 63;
        tileT[a][b] = adj[(size_t)(c0 + a) * Nn_ + r0 + b];
    }
    __syncthreads();
    // direct orientation: S1p, S0Tp (read adj rows straight, coalesced)
    for (int it = t; it < 512; it += 256) {
        int ii = it >> 3, kc = it & 7;
        int r = r0 + ii, cb = c0 + kc * 8;
        float rv = rinv[r];
        bf16x8 v1, v0t;
#pragma unroll
        for (int e = 0; e < 8; ++e) {
            float a = adj[(size_t)r * Nn_ + cb + e];
            v1[e]  = f2bf(a * cinv[cb + e]);
            v0t[e] = f2bf(a * rv);
        }
        size_t off = poff(r, cb);
        *(bf16x8*)(S1p + off)  = v1;
        *(bf16x8*)(S0Tp + off) = v0t;
    }
    // transposed orientation: S0p, S1Tp (gather from LDS tile)
    for (int it = t; it < 512; it += 256) {
        int ii = it >> 3, kc = it & 7;
        int r = r0 + ii, cb = c0 + kc * 8;
        float cv = cinv[r];
        bf16x8 v0, v1t;
#pragma unroll
        for (int e = 0; e < 8; ++e) {
            float a = tileT[kc * 8 + e][ii];    // adj[c0+kc*8+e][r0+ii]
            v0[e]  = f2bf(a * rinv[cb + e]);
            v1t[e] = f2bf(a * cv);
        }
        size_t off = poff(r, cb);
        *(bf16x8*)(S0p + off)  = v0;
        *(bf16x8*)(S1Tp + off) = v1t;
    }
}

// ---------------- operand packing ----------------
// Layout: X[k][(p*Bb + b)][n]  — p-major so state rows (p>=16) are one contiguous
// 2048-row block, allowing the c-path diffusion to recompute only those rows.

__global__ void build_x0_kernel(const float* __restrict__ inputs, const float* __restrict__ state,
                                short* __restrict__ x0) {
    const int b = blockIdx.y, n0 = blockIdx.x * 64;
    __shared__ float sIn[64][17];
    __shared__ float sSt[64][65];
    const int t = threadIdx.x;
    const float* ip = inputs + ((size_t)b * Nn_ + n0) * DESCn;
    for (int i = t; i < 64 * DESCn; i += 256) sIn[i >> 4][i & 15] = ip[i];
    const float* sp = state + ((size_t)b * Nn_ + n0) * Hn;
    for (int i = t; i < 64 * Hn; i += 256) sSt[i >> 6][i & 63] = sp[i];
    __syncthreads();
    for (int i = t; i < Pn * 64; i += 256) {
        int pp = i >> 6, nn = i & 63;
        float v = (pp < DESCn) ? sIn[nn][pp] : sSt[nn][pp - DESCn];
        x0[((size_t)pp * Bb + b) * Nn_ + n0 + nn] = f2bf(v);
    }
}

// one kernel for all three theta reorders: T[k][h][96] = theta[(p*5+k)*64+h], 0-pad p>=80
__global__ void reorder_theta3_kernel(const float* __restrict__ thR, const float* __restrict__ thU,
                                      const float* __restrict__ thC, short* __restrict__ TR,
                                      short* __restrict__ TU, short* __restrict__ TC) {
    int i = blockIdx.x * 256 + threadIdx.x;
    if (i >= KM * 64 * 96) return;
    int k = i / (64 * 96);
    int rem = i % (64 * 96);
    int h = rem / 96, pp = rem % 96;
    if (pp < Pn) {
        size_t idx = ((size_t)pp * KM + k) * Hn + h;
        TR[i] = f2bf(thR[idx]);
        TU[i] = f2bf(thU[idx]);
        TC[i] = f2bf(thC[idx]);
    } else {
        TR[i] = 0; TU[i] = 0; TC[i] = 0;
    }
}

// ---------------- main diffusion GEMM: 256x256 tile, B-from-global ------------
// D[c][m] = sum_n A[c][n] * Bm[m][n]  (A row-major or packed; Bm PACKED; D row-major or packed)
// 512 threads = 8 waves (2 wm x 4 wn); per-wave output 128x64; BK=64.
// LDS 64 KiB: A only, [2 dbuf][2 half][128][64] (swizzled image as before).
// B operand: loaded global->VGPR from the packed layout — one fragment = 1 KB
// contiguous per wave (coalesced dwordx4), L2-resident. This removes B's glds
// writes (32 KB) and B's ds_reads (64 KB) per K-step per CU: LDS term drops
// from ~2320 to ~1430 cyc < MFMA term (~2060 cyc) -> windows become MFMA-bound.
// Single rB bank [2][2][2]; role-dependent prefetch distance:
//   role 0: stage A(t+1); LOADA(t); MMAQ(ch0); loadB(t+1,ch0); MMAQ(ch1); loadB(t+1,ch1)
//   role 1: stage A(t+1); MMAQ(t-1,ch0); loadB(t,ch0); MMAQ(t-1,ch1); loadB(t,ch1); LOADA(t)
// WAR on rB/rA by program order (load issued after consuming MFMA issues);
// RAW by vmcnt(0)+barrier each window. Both roles accumulate in identical
// K-order -> bitwise-identical results.

struct GemmJob  { const short* A; const short* B; short* D; int yStart; int aPacked; int packD; };
struct GemmJobs { GemmJob j[4]; };

#define MMAQ(RH, CH)                                                            \
    _Pragma("unroll")                                                           \
    for (int ks = 0; ks < 2; ++ks)                                              \
        _Pragma("unroll")                                                       \
        for (int fm = 0; fm < 4; ++fm)                                          \
            _Pragma("unroll")                                                   \
            for (int fn = 0; fn < 2; ++fn)                                      \
                acc[RH][CH][fm][fn] = __builtin_amdgcn_mfma_f32_16x16x32_bf16(  \
                    rA[RH][fm][ks], rB[CH][fn][ks], acc[RH][CH][fm][fn], 0, 0, 0);

#define LOADA(D_)                                                               \
    _Pragma("unroll")                                                           \
    for (int rh = 0; rh < 2; ++rh)                                              \
        _Pragma("unroll")                                                       \
        for (int fm = 0; fm < 4; ++fm)                                          \
            _Pragma("unroll")                                                   \
            for (int ks = 0; ks < 2; ++ks)                                      \
                rA[rh][fm][ks] = readA(D_, rh, fm, ks);

// window end: LDS reads drained (WAR for next stage), glds+B-loads drained (RAW)
#define SYNCK()                                                   \
    asm volatile("s_waitcnt lgkmcnt(0)" ::: "memory");            \
    __builtin_amdgcn_sched_barrier(0);                            \
    asm volatile("s_waitcnt vmcnt(0)" ::: "memory");              \
    __builtin_amdgcn_s_barrier();                                 \
    __builtin_amdgcn_sched_barrier(0);

__global__ __launch_bounds__(512, 2)
void gemm_bt_256(GemmJobs jobs, int nJobs, int K, int NN) {
    __shared__ __align__(16) short lds[32768];   // 64 KiB (A dbuf; epilogue reuses)

    const int by = blockIdx.y;
    int jsel = 0;
#pragma unroll
    for (int q = 1; q < 4; ++q)
        if (q < nJobs && by >= jobs.j[q].yStart) jsel = q;
    const GemmJob jb = jobs.j[jsel];
    const short* __restrict__ A  = jb.A;
    const short* __restrict__ Bp = jb.B;       // packed
    short* __restrict__ D = jb.D;
    const int aPacked = jb.aPacked, packD = jb.packD;

    const int c0 = (by - jb.yStart) * 256;
    const int m0 = blockIdx.x * 256;
    const int mt = blockIdx.x;                 // packed B block row
    const int tid = threadIdx.x;
    const int w = tid >> 6, lane = tid & 63;
    const int wm = w >> 2, wn = w & 3;
    const int l16 = lane & 15, g = lane >> 4;
    const int swz = l16 & 7;
    const int role = (w ^ (w >> 2)) & 1;       // one of each per SIMD

    // A staging geometry: one glds issue = 512 thr x 16B = 8 KB = 64 rows x 64 cols
    const int srow = tid >> 3;                       // 0..63
    const int skc  = (tid & 7) ^ (srow & 7);         // inverse-swizzled source k-group
    const int scol = skc * 8;
    const int stOff = w * 512;                       // wave-uniform LDS offset (shorts)

    const short* Abase = A + (size_t)c0 * K;
    const int KS = K >> 6;                           // 32

    auto stageA = [&](int h, int t) {
        short* lb = lds + ((t & 1) * 16384 + h * 8192) + stOff;
        if (!aPacked) {
            const short* gb = Abase + (size_t)(h * 128) * K + t * 64 + scol;
#pragma unroll
            for (int i = 0; i < 2; ++i)
                glds16(gb + (size_t)(i * 64 + srow) * K, lb + i * 4096);
        } else {
#pragma unroll
            for (int i = 0; i < 2; ++i) {
                int r = c0 + h * 128 + i * 64 + srow;
                const short* gs = A + ((((size_t)(r >> 8) * 32 + t) * 16 + ((r >> 4) & 15)) * 2
                                       + (skc >> 2)) * 512
                                    + (size_t)((skc & 3) * 128 + (r & 15) * 8);
                glds16(gs, lb + i * 4096);
            }
        }
    };

    auto readA = [&](int d, int rh, int fm, int ks) -> bf16x8 {
        int r7 = rh * 64 + fm * 16 + l16;
        int idx = d * 16384 + wm * 8192 + r7 * 64 + (((ks * 4 + g) ^ swz) * 8);
        return *(const bf16x8*)(lds + idx);
    };

    bf16x8 rA[2][4][2], rB[2][2][2];

    auto loadB = [&](int t, int ch, int fn) {
        size_t blk = ((((size_t)mt * 32 + t) * 16 + (wn * 4 + ch * 2 + fn)) * 2) * 512
                     + (size_t)lane * 8;
        rB[ch][fn][0] = *(const bf16x8*)(Bp + blk);
        rB[ch][fn][1] = *(const bf16x8*)(Bp + blk + 512);
    };

    f32x4 acc[2][2][4][2];   // [rh][ch][fm][fn]
    const f32x4 fz = {0.f, 0.f, 0.f, 0.f};
#pragma unroll
    for (int a = 0; a < 2; ++a)
#pragma unroll
        for (int b = 0; b < 2; ++b)
#pragma unroll
            for (int c = 0; c < 4; ++c)
#pragma unroll
                for (int d = 0; d < 2; ++d) acc[a][b][c][d] = fz;

    // prologue: stage A(0), load B(0)
    stageA(0, 0); stageA(1, 0);
    loadB(0, 0, 0); loadB(0, 0, 1); loadB(0, 1, 0); loadB(0, 1, 1);
    asm volatile("s_waitcnt vmcnt(0)" ::: "memory");
    __builtin_amdgcn_s_barrier();
    __builtin_amdgcn_sched_barrier(0);

#pragma unroll 1
    for (int t = 0; t < KS; ++t) {
        const int cur = t & 1;
        if (t + 1 < KS) { stageA(0, t + 1); stageA(1, t + 1); }
        if (role) {
            // compute K-step t-1 (registers from last window), prefetch B(t)
            if (t) {
                __builtin_amdgcn_s_setprio(1);
                MMAQ(0, 0); MMAQ(1, 0);
                __builtin_amdgcn_s_setprio(0);
                loadB(t, 0, 0); loadB(t, 0, 1);
                __builtin_amdgcn_s_setprio(1);
                MMAQ(0, 1); MMAQ(1, 1);
                __builtin_amdgcn_s_setprio(0);
                loadB(t, 1, 0); loadB(t, 1, 1);
            } else {
                loadB(0, 0, 0); loadB(0, 0, 1); loadB(0, 1, 0); loadB(0, 1, 1);
            }
            LOADA(cur);
        } else {
            // compute K-step t, prefetch B(t+1)
            LOADA(cur);
            __builtin_amdgcn_s_setprio(1);
            MMAQ(0, 0); MMAQ(1, 0);
            __builtin_amdgcn_s_setprio(0);
            if (t + 1 < KS) { loadB(t + 1, 0, 0); loadB(t + 1, 0, 1); }
            __builtin_amdgcn_s_setprio(1);
            MMAQ(0, 1); MMAQ(1, 1);
            __builtin_amdgcn_s_setprio(0);
            if (t + 1 < KS) { loadB(t + 1, 1, 0); loadB(t + 1, 1, 1); }
        }
        SYNCK();
    }
    if (role) {   // K-step KS-1 (register-only tail)
        __builtin_amdgcn_s_setprio(1);
        MMAQ(0, 0); MMAQ(1, 0); MMAQ(0, 1); MMAQ(1, 1);
        __builtin_amdgcn_s_setprio(0);
    }

    // ---------------- epilogue: per-wave LDS transpose -> coalesced stores ----
    __syncthreads();
    float* tb = (float*)lds + w * 1088;   // 16x68 f32 per wave (8 x 4352 B = 34 KB)
    const int r8 = lane >> 3;             // 0..7
    const int cg = (lane & 7) * 8;        // col group (8 cols)
    const int mb = m0 + wn * 64;
#pragma unroll
    for (int rh = 0; rh < 2; ++rh)
#pragma unroll
        for (int fm = 0; fm < 4; ++fm) {
#pragma unroll
            for (int ch = 0; ch < 2; ++ch)
#pragma unroll
                for (int fn = 0; fn < 2; ++fn) {
                    f32x4 v = acc[rh][ch][fm][fn];
#pragma unroll
                    for (int r = 0; r < 4; ++r)
                        tb[(g * 4 + r) * 68 + ch * 32 + fn * 16 + l16] = v[r];
                }
            const int crow0 = c0 + wm * 128 + rh * 64 + fm * 16;
            if (!packD) {
#pragma unroll
                for (int ii = 0; ii < 2; ++ii) {
                    int row = ii * 8 + r8;
                    bf16x8 pk;
#pragma unroll
                    for (int jj = 0; jj < 8; ++jj) pk[jj] = f2bf(tb[row * 68 + cg + jj]);
                    *(bf16x8*)(D + (size_t)(crow0 + row) * NN + mb - wn * 64 + wn * 64 + cg) = pk;
                }
            } else {
                // packed write: chunk = rows [crow0,crow0+16) x cols [mb,mb+64)
                // = one 1024-short packed region; lane writes shorts lane*16..+15
                size_t bb = (((size_t)(crow0 >> 8) * 32 + (mb >> 6)) * 16 + ((crow0 >> 4) & 15)) * 1024;
                int ro0 = (2 * lane) & 15, ro1 = (2 * lane + 1) & 15;
                int cb = (lane >> 3) * 8;
                bf16x8 p0, p1;
#pragma unroll
                for (int jj = 0; jj < 8; ++jj) {
                    p0[jj] = f2bf(tb[ro0 * 68 + cb + jj]);
                    p1[jj] = f2bf(tb[ro1 * 68 + cb + jj]);
                }
                *(bf16x8*)(D + bb + (size_t)lane * 16) = p0;
                *(bf16x8*)(D + bb + (size_t)lane * 16 + 8) = p1;
            }
        }
}

// ---------------- theta projections ----------------

__global__ __launch_bounds__(256, 2)
void theta_ru_kernel(const short* __restrict__ X, const short* __restrict__ ThR,
                     const short* __restrict__ ThU, const float* __restrict__ biasR,
                     const float* __restrict__ biasU, const float* __restrict__ state,
                     short* __restrict__ Uout, short* __restrict__ x0) {
    __shared__ short ldsAr[64 * 40];
    __shared__ short ldsAu[64 * 40];
    __shared__ short ldsB[32 * 136];
    const int b = blockIdx.y, n0 = blockIdx.x * 128;
    const int t = threadIdx.x, w = t >> 6, lane = t & 63;
    const int l16 = lane & 15, g = lane >> 4;
    const f32x4 fz = {0.f, 0.f, 0.f, 0.f};
    const bf16x8 bz = {0, 0, 0, 0, 0, 0, 0, 0};

    f32x4 aR[4][2], aU[4][2];   // [mi][nj]
#pragma unroll
    for (int i = 0; i < 4; i++)
#pragma unroll
        for (int j = 0; j < 2; j++) { aR[i][j] = fz; aU[i][j] = fz; }

    const int hA = t >> 2, pcA = (t & 3) * 8;

    for (int kb = 0; kb < KM; kb++) {
        for (int ks = 0; ks < 3; ks++) {
            __syncthreads();
            *(bf16x8*)(ldsAr + hA * 40 + pcA) =
                *(const bf16x8*)(ThR + ((size_t)kb * 64 + hA) * 96 + ks * 32 + pcA);
            *(bf16x8*)(ldsAu + hA * 40 + pcA) =
                *(const bf16x8*)(ThU + ((size_t)kb * 64 + hA) * 96 + ks * 32 + pcA);
#pragma unroll
            for (int i = 0; i < 2; i++) {
                int q = t + i * 256;
                int pp = q >> 4, nc = (q & 15) * 8;
                int pg = ks * 32 + pp;
                bf16x8 v = bz;
                if (pg < Pn)
                    v = *(const bf16x8*)(X + (size_t)kb * XSTRIDE + ((size_t)pg * Bb + b) * Nn_ + n0 + nc);
                *(bf16x8*)(ldsB + pp * 136 + nc) = v;
            }
            __syncthreads();
            bf16x8 ar[4], au[4];
#pragma unroll
            for (int mi = 0; mi < 4; mi++) {
                int hr = mi * 16 + l16;
                ar[mi] = *(const bf16x8*)(ldsAr + hr * 40 + g * 8);
                au[mi] = *(const bf16x8*)(ldsAu + hr * 40 + g * 8);
            }
#pragma unroll
            for (int nj = 0; nj < 2; nj++) {
                int col = w * 32 + nj * 16 + l16;
                bf16x8 bv;
#pragma unroll
                for (int j = 0; j < 8; j++) bv[j] = ldsB[(g * 8 + j) * 136 + col];
#pragma unroll
                for (int mi = 0; mi < 4; mi++) {
                    aR[mi][nj] = __builtin_amdgcn_mfma_f32_16x16x32_bf16(ar[mi], bv, aR[mi][nj], 0, 0, 0);
                    aU[mi][nj] = __builtin_amdgcn_mfma_f32_16x16x32_bf16(au[mi], bv, aU[mi][nj], 0, 0, 0);
                }
            }
        }
    }
#pragma unroll
    for (int mi = 0; mi < 4; mi++)
#pragma unroll
        for (int nj = 0; nj < 2; nj++) {
            int n = n0 + w * 32 + nj * 16 + l16;
            int h0 = mi * 16 + g * 4;
            size_t base = ((size_t)b * Nn_ + n) * Hn + h0;
            f32x4 st = *(const f32x4*)(state + base);
            s16x4 uv;
#pragma unroll
            for (int r = 0; r < 4; r++) {
                float zr = aR[mi][nj][r] + biasR[h0 + r];
                float zu = aU[mi][nj][r] + biasU[h0 + r];
                float rr = 1.f / (1.f + __expf(-zr));
                uv[r] = f2bf(1.f / (1.f + __expf(-zu)));
                x0[((size_t)(DESCn + h0 + r) * Bb + b) * Nn_ + n] = f2bf(rr * st[r]);
            }
            *(s16x4*)(Uout + base) = uv;
        }
}

__global__ __launch_bounds__(256, 2)
void theta_c_kernel(const short* __restrict__ X, const short* __restrict__ ThC,
                    const float* __restrict__ biasC, const short* __restrict__ U,
                    const float* __restrict__ state, float* __restrict__ out) {
    __shared__ short ldsA[64 * 40];
    __shared__ short ldsB[32 * 136];
    const int b = blockIdx.y, n0 = blockIdx.x * 128;
    const int t = threadIdx.x, w = t >> 6, lane = t & 63;
    const int l16 = lane & 15, g = lane >> 4;
    const f32x4 fz = {0.f, 0.f, 0.f, 0.f};
    const bf16x8 bz = {0, 0, 0, 0, 0, 0, 0, 0};

    f32x4 aC[4][2];
#pragma unroll
    for (int i = 0; i < 4; i++)
#pragma unroll
        for (int j = 0; j < 2; j++) aC[i][j] = fz;

    const int hA = t >> 2, pcA = (t & 3) * 8;

    for (int kb = 0; kb < KM; kb++) {
        for (int ks = 0; ks < 3; ks++) {
            __syncthreads();
            *(bf16x8*)(ldsA + hA * 40 + pcA) =
                *(const bf16x8*)(ThC + ((size_t)kb * 64 + hA) * 96 + ks * 32 + pcA);
#pragma unroll
            for (int i = 0; i < 2; i++) {
                int q = t + i * 256;
                int pp = q >> 4, nc = (q & 15) * 8;
                int pg = ks * 32 + pp;
                bf16x8 v = bz;
                if (pg < Pn)
                    v = *(const bf16x8*)(X + (size_t)kb * XSTRIDE + ((size_t)pg * Bb + b) * Nn_ + n0 + nc);
                *(bf16x8*)(ldsB + pp * 136 + nc) = v;
            }
            __syncthreads();
            bf16x8 ac[4];
#pragma unroll
            for (int mi = 0; mi < 4; mi++)
                ac[mi] = *(const bf16x8*)(ldsA + (mi * 16 + l16) * 40 + g * 8);
#pragma unroll
            for (int nj = 0; nj < 2; nj++) {
                int col = w * 32 + nj * 16 + l16;
                bf16x8 bv;
#pragma unroll
                for (int j = 0; j < 8; j++) bv[j] = ldsB[(g * 8 + j) * 136 + col];
#pragma unroll
                for (int mi = 0; mi < 4; mi++)
                    aC[mi][nj] = __builtin_amdgcn_mfma_f32_16x16x32_bf16(ac[mi], bv, aC[mi][nj], 0, 0, 0);
            }
        }
    }
#pragma unroll
    for (int mi = 0; mi < 4; mi++)
#pragma unroll
        for (int nj = 0; nj < 2; nj++) {
            int n = n0 + w * 32 + nj * 16 + l16;
            int h0 = mi * 16 + g * 4;
            size_t base = ((size_t)b * Nn_ + n) * Hn + h0;
            f32x4 st = *(const f32x4*)(state + base);
            s16x4 uv = *(const s16x4*)(U + base);
            f32x4 o;
#pragma unroll
            for (int r = 0; r < 4; r++) {
                float cc = tanhf(aC[mi][nj][r] + biasC[h0 + r]);
                float uu = bf2f(uv[r]);
                o[r] = uu * st[r] + (1.f - uu) * cc;
            }
            *(f32x4*)(out + base) = o;
        }
}

// ---------------- launcher ----------------

extern "C" void kernel_launch(void* const* d_in, const int* in_sizes, int n_in,
                              void* d_out, int out_size, void* d_ws, size_t ws_size,
                              hipStream_t stream) {
    (void)in_sizes; (void)n_in; (void)out_size; (void)ws_size;
    const float* inputs = (const float*)d_in[0];
    const float* state  = (const float*)d_in[1];
    const float* adj    = (const float*)d_in[2];
    const float* thR    = (const float*)d_in[3];
    const float* thU    = (const float*)d_in[4];
    const float* thC    = (const float*)d_in[5];
    const float* bR     = (const float*)d_in[6];
    const float* bU     = (const float*)d_in[7];
    const float* bC     = (const float*)d_in[8];
    float* out = (float*)d_out;

    char* p = (char*)d_ws;
    auto alloc = [&](size_t bytes) -> void* {
        void* r = (void*)p;
        p += (bytes + 255) & ~(size_t)255;
        return r;
    };
    short* S0p   = (short*)alloc((size_t)Nn_ * Nn_ * 2);
    short* S1p   = (short*)alloc((size_t)Nn_ * Nn_ * 2);
    short* S0Tp  = (short*)alloc((size_t)Nn_ * Nn_ * 2);
    short* S1Tp  = (short*)alloc((size_t)Nn_ * Nn_ * 2);
    short* Ssq0p = (short*)alloc((size_t)Nn_ * Nn_ * 2);
    short* Ssq1p = (short*)alloc((size_t)Nn_ * Nn_ * 2);
    float* rinv = (float*)alloc(Nn_ * 4);
    float* cinv = (float*)alloc(Nn_ * 4);
    float* sums = (float*)alloc(2 * Nn_ * 4);   // rsum | csum
    short* xb   = (short*)alloc(5 * XSTRIDE * 2);
    short* TR   = (short*)alloc((size_t)KM * 64 * 96 * 2);
    short* TU   = (short*)alloc((size_t)KM * 64 * 96 * 2);
    short* TC   = (short*)alloc((size_t)KM * 64 * 96 * 2);
    short* Ub   = (short*)alloc((size_t)Bb * Nn_ * Hn * 2);

    short* x0 = xb;
    short* y1 = xb + 1 * XSTRIDE;
    short* y2 = xb + 2 * XSTRIDE;
    short* y3 = xb + 3 * XSTRIDE;
    short* y4 = xb + 4 * XSTRIDE;
    const size_t HOFF = (size_t)DESCn * Bb * Nn_;   // start of state-feature rows

    hipMemsetAsync(sums, 0, 2 * Nn_ * 4, stream);
    sums_kernel<<<dim3(32, 32), 256, 0, stream>>>(adj, sums, sums + Nn_);
    inv2_kernel<<<Nn_ / 256, 256, 0, stream>>>(sums, sums + Nn_, rinv, cinv);
    build_S_kernel<<<dim3(32, 32), 256, 0, stream>>>(adj, rinv, cinv, S0p, S1p, S0Tp, S1Tp);
    build_x0_kernel<<<dim3(32, Bb), 256, 0, stream>>>(inputs, state, x0);
    int rt_grid = (KM * 64 * 96 + 255) / 256;
    reorder_theta3_kernel<<<rt_grid, 256, 0, stream>>>(thR, thU, thC, TR, TU, TC);

    // D1 (208 blocks): Ssq0 = S0*S0 (packed out), Ssq1 = S1*S1 (packed out), y1 = S0 x0
    GemmJobs d1;
    d1.j[0] = { S0p, S0Tp, Ssq0p, 0, 1, 1 };
    d1.j[1] = { S1p, S1Tp, Ssq1p, 8, 1, 1 };
    d1.j[2] = { x0, S0p,   y1, 16, 0, 0 };
    d1.j[3] = d1.j[2];
    gemm_bt_256<<<dim3(8, 26), 512, 0, stream>>>(d1, 3, Nn_, Nn_);

    // D2 (240 blocks): y3 = S1 x0, y2 = Ssq0 x0, y4 = Ssq1 x0
    GemmJobs d2;
    d2.j[0] = { x0, S1p,   y3, 0, 0, 0 };
    d2.j[1] = { x0, Ssq0p, y2, 10, 0, 0 };
    d2.j[2] = { x0, Ssq1p, y4, 20, 0, 0 };
    d2.j[3] = d2.j[2];
    gemm_bt_256<<<dim3(8, 30), 512, 0, stream>>>(d2, 3, Nn_, Nn_);

    theta_ru_kernel<<<dim3(Nn_ / 128, Bb), 256, 0, stream>>>(xb, TR, TU, bR, bU, state, Ub, x0);

    // D3 (256 blocks): c-path, state-feature rows only (input rows unchanged)
    GemmJobs d3;
    d3.j[0] = { x0 + HOFF, S0p,   y1 + HOFF, 0, 0, 0 };
    d3.j[1] = { x0 + HOFF, Ssq0p, y2 + HOFF, 8, 0, 0 };
    d3.j[2] = { x0 + HOFF, S1p,   y3 + HOFF, 16, 0, 0 };
    d3.j[3] = { x0 + HOFF, Ssq1p, y4 + HOFF, 24, 0, 0 };
    gemm_bt_256<<<dim3(8, 32), 512, 0, stream>>>(d3, 4, Nn_, Nn_);

    theta_c_kernel<<<dim3(Nn_ / 128, Bb), 256, 0, stream>>>(xb, TC, bC, Ub, state, out);
}

// Round 7
// 246.760 us; speedup vs baseline: 7.2523x; 7.2523x over previous
//
#include <hip/hip_runtime.h>
#include <hip/hip_bf16.h>

#define Bb    32
#define Nn_   2048
#define DESCn 16
#define Hn    64
#define Pn    80
#define KM    5

#define XSTRIDE ((size_t)Bb * Pn * Nn_)   // elements per diffusion buffer (2560*2048)

typedef __attribute__((ext_vector_type(8))) short bf16x8;
typedef __attribute__((ext_vector_type(4))) short s16x4;
typedef __attribute__((ext_vector_type(4))) float f32x4;

__device__ __forceinline__ short f2bf(float f) {
    unsigned u = __builtin_bit_cast(unsigned, f);
    u = u + 0x7FFFu + ((u >> 16) & 1u);
    return (short)(u >> 16);
}
__device__ __forceinline__ float bf2f(short s) {
    unsigned u = ((unsigned)(unsigned short)s) << 16;
    return __builtin_bit_cast(float, u);
}

__device__ __forceinline__ void glds16(const void* g, void* l) {
    __builtin_amdgcn_global_load_lds((const __attribute__((address_space(1))) void*)g,
                                     (__attribute__((address_space(3))) void*)l, 16, 0, 0);
}

// ---------------- support construction ----------------

// one pass over adj: per-64x64-tile row sums and col sums, atomically accumulated
__global__ void sums_kernel(const float* __restrict__ adj, float* __restrict__ rsum,
                            float* __restrict__ csum) {
    __shared__ float tile[64][65];
    const int r0 = blockIdx.y * 64, c0 = blockIdx.x * 64;
    const int t = threadIdx.x;
    for (int i = t; i < 64 * 64; i += 256)
        tile[i >> 6][i & 63] = adj[(size_t)(r0 + (i >> 6)) * Nn_ + c0 + (i & 63)];
    __syncthreads();
    if (t < 64) {
        float s = 0.f;
#pragma unroll 8
        for (int j = 0; j < 64; ++j) s += tile[t][j];
        atomicAdd(&rsum[r0 + t], s);
    } else if (t < 128) {
        int c = t - 64;
        float s = 0.f;
#pragma unroll 8
        for (int j = 0; j < 64; ++j) s += tile[j][c];
        atomicAdd(&csum[c0 + c], s);
    }
}

// Outputs (all row-major [i][j], bf16); inverse degrees computed inline from sums:
//   S1 [i][j] = adj[i][j] * cinv[j]
//   S0T[i][j] = adj[i][j] * rinv[i]     (= S0^T)
//   S0 [i][j] = adj[j][i] * rinv[j]
//   S1T[i][j] = adj[j][i] * cinv[i]     (= S1^T)
__global__ void build_S_kernel(const float* __restrict__ adj, const float* __restrict__ rsum,
                               const float* __restrict__ csum, short* __restrict__ S0,
                               short* __restrict__ S1, short* __restrict__ S0T,
                               short* __restrict__ S1T) {
    __shared__ float tile[64][65];            // tile[a][b] = adj[c0+a][r0+b]
    __shared__ float riv[64], civ[64], rivC[64], civR[64];
    int r0 = blockIdx.y * 64, c0 = blockIdx.x * 64;
    const int tt = threadIdx.x;
    if (tt < 64) {
        float rs = rsum[r0 + tt], cs = csum[c0 + tt];
        riv[tt] = rs > 0.f ? 1.f / rs : 0.f;      // rinv over rows r0..
        civ[tt] = cs > 0.f ? 1.f / cs : 0.f;      // cinv over cols c0..
        float rsc = rsum[c0 + tt], csr = csum[r0 + tt];
        rivC[tt] = rsc > 0.f ? 1.f / rsc : 0.f;   // rinv over cols c0..
        civR[tt] = csr > 0.f ? 1.f / csr : 0.f;   // cinv over rows r0..
    }
    for (int i = tt; i < 64 * 64; i += 256) {
        int a = i >> 6, b = i & 63;
        tile[a][b] = adj[(size_t)(c0 + a) * Nn_ + r0 + b];
    }
    __syncthreads();
    for (int i = tt; i < 64 * 64; i += 256) {
        int r = i >> 6, c = i & 63;
        float a = adj[(size_t)(r0 + r) * Nn_ + c0 + c];
        size_t o = (size_t)(r0 + r) * Nn_ + c0 + c;
        S1[o]  = f2bf(a * civ[c]);
        S0T[o] = f2bf(a * riv[r]);
    }
    for (int i = tt; i < 64 * 64; i += 256) {
        int r = i >> 6, c = i & 63;
        float at = tile[c][r];                 // adj[c0+c][r0+r]
        size_t o = (size_t)(r0 + r) * Nn_ + c0 + c;
        S0[o]  = f2bf(at * rivC[c]);
        S1T[o] = f2bf(at * civR[r]);
    }
}

// ---------------- operand packing ----------------
// Layout: X[k][(p*Bb + b)][n]  — p-major so state rows (p>=16) are one contiguous
// 2048-row block, allowing the c-path diffusion to recompute only those rows.

__global__ void build_x0_kernel(const float* __restrict__ inputs, const float* __restrict__ state,
                                short* __restrict__ x0) {
    const int b = blockIdx.y, n0 = blockIdx.x * 64;
    __shared__ float sIn[64][17];
    __shared__ float sSt[64][65];
    const int t = threadIdx.x;
    const float* ip = inputs + ((size_t)b * Nn_ + n0) * DESCn;
    for (int i = t; i < 64 * DESCn; i += 256) sIn[i >> 4][i & 15] = ip[i];
    const float* sp = state + ((size_t)b * Nn_ + n0) * Hn;
    for (int i = t; i < 64 * Hn; i += 256) sSt[i >> 6][i & 63] = sp[i];
    __syncthreads();
    for (int i = t; i < Pn * 64; i += 256) {
        int pp = i >> 6, nn = i & 63;
        float v = (pp < DESCn) ? sIn[nn][pp] : sSt[nn][pp - DESCn];
        x0[((size_t)pp * Bb + b) * Nn_ + n0 + nn] = f2bf(v);
    }
}

// one kernel for all three theta reorders: T[k][h][96] = theta[(p*5+k)*64+h], 0-pad p>=80
__global__ void reorder_theta3_kernel(const float* __restrict__ thR, const float* __restrict__ thU,
                                      const float* __restrict__ thC, short* __restrict__ TR,
                                      short* __restrict__ TU, short* __restrict__ TC) {
    int i = blockIdx.x * 256 + threadIdx.x;
    if (i >= KM * 64 * 96) return;
    int k = i / (64 * 96);
    int rem = i % (64 * 96);
    int h = rem / 96, pp = rem % 96;
    if (pp < Pn) {
        size_t idx = ((size_t)pp * KM + k) * Hn + h;
        TR[i] = f2bf(thR[idx]);
        TU[i] = f2bf(thU[idx]);
        TC[i] = f2bf(thC[idx]);
    } else {
        TR[i] = 0; TU[i] = 0; TC[i] = 0;
    }
}

// ---------------- main diffusion GEMM: 256x256 tile, role-staggered windows ----
// D[c][m] = sum_n A[c][n] * Bm[m][n]  (bf16 row-major; A,Bm ld=K; D ld=NN)
// Heterogeneous jobs packed along blockIdx.y: job j owns by in [yStart_j, yStart_{j+1}).
// 512 threads = 8 waves (2 wm x 4 wn); per-wave output 128x64; BK=64, dbuf over K-steps.
// LDS 128 KiB: A [2 dbuf][2 half][128][64] @0, B same @32768 shorts.
// Swizzle: byte ^= (row&7)<<4 via inverse-permuted global source + swizzled reads.
//
// ROLE STAGGER (verified 58.7 us/dispatch): the two waves sharing a SIMD take
// complementary in-window orders; staging, read sets, lgkm/vmcnt/barrier
// positions identical to the verified 4-window schedule.

struct GemmJob  { const short* A; const short* B; short* D; int yStart; };
struct GemmJobs { GemmJob j[4]; };

#define MMAQ(RH, CH, RB)                                                        \
    {                                                                           \
        __builtin_amdgcn_s_setprio(1);                                          \
        _Pragma("unroll")                                                       \
        for (int ks = 0; ks < 2; ++ks)                                          \
            _Pragma("unroll")                                                   \
            for (int fm = 0; fm < 4; ++fm)                                      \
                _Pragma("unroll")                                               \
                for (int fn = 0; fn < 2; ++fn)                                  \
                    acc[RH][CH][fm][fn] = __builtin_amdgcn_mfma_f32_16x16x32_bf16( \
                        rA[fm][ks], RB[fn][ks], acc[RH][CH][fm][fn], 0, 0, 0);  \
        __builtin_amdgcn_s_setprio(0);                                          \
    }

#define LOADA(D_, RH)                                                           \
    _Pragma("unroll")                                                           \
    for (int fm = 0; fm < 4; ++fm)                                              \
        _Pragma("unroll")                                                       \
        for (int ks = 0; ks < 2; ++ks)                                          \
            rA[fm][ks] = readA(D_, RH, fm, ks);

#define LOADB(D_, CH, RB)                                                       \
    _Pragma("unroll")                                                           \
    for (int fn = 0; fn < 2; ++fn)                                              \
        _Pragma("unroll")                                                       \
        for (int ks = 0; ks < 2; ++ks)                                          \
            RB[fn][ks] = readB(D_, CH, fn, ks);

// window end: all LDS reads drained, then barrier (deterministic WAR guard)
#define SYNCW()                                                   \
    asm volatile("s_waitcnt lgkmcnt(0)" ::: "memory");            \
    __builtin_amdgcn_sched_barrier(0);                            \
    __builtin_amdgcn_s_barrier();                                 \
    __builtin_amdgcn_sched_barrier(0);

// window end at K-step boundary: additionally drain glds queue down to 4
#define SYNCWV()                                                  \
    asm volatile("s_waitcnt lgkmcnt(0)" ::: "memory");            \
    __builtin_amdgcn_sched_barrier(0);                            \
    asm volatile("s_waitcnt vmcnt(4)" ::: "memory");              \
    __builtin_amdgcn_s_barrier();                                 \
    __builtin_amdgcn_sched_barrier(0);

__global__ __launch_bounds__(512, 2)
void gemm_bt_256(GemmJobs jobs, int nJobs, int K, int NN) {
    __shared__ __align__(16) short lds[65536];   // 128 KiB

    // job selection from packed blockIdx.y
    const int by = blockIdx.y;
    int jsel = 0;
#pragma unroll
    for (int q = 1; q < 4; ++q)
        if (q < nJobs && by >= jobs.j[q].yStart) jsel = q;
    const GemmJob jb = jobs.j[jsel];
    const short* __restrict__ A  = jb.A;
    const short* __restrict__ Bm = jb.B;
    short* __restrict__ D = jb.D;

    const int c0 = (by - jb.yStart) * 256;
    const int m0 = blockIdx.x * 256;
    const int tid = threadIdx.x;
    const int w = tid >> 6, lane = tid & 63;
    const int wm = w >> 2, wn = w & 3;
    const int l16 = lane & 15, g = lane >> 4;
    const int swz = l16 & 7;
    const int role = (w ^ (w >> 2)) & 1;   // one of each per SIMD (either pairing)

    // staging geometry: one glds issue = 512 thr x 16B = 8 KB = 64 rows of 64 cols
    const int srow = tid >> 3;                       // 0..63
    const int scol = ((tid & 7) ^ (srow & 7)) * 8;   // inverse-swizzled source col (elements)
    const int stOff = w * 512;                       // wave-uniform LDS offset (shorts)

    const short* Abase = A + (size_t)c0 * K;
    const short* Bbase = Bm + (size_t)m0 * K;

    auto stageA = [&](int h, int t) {
        const short* gb = Abase + (size_t)(h * 128) * K + t * 64 + scol;
        short* lb = lds + ((t & 1) * 16384 + h * 8192) + stOff;
#pragma unroll
        for (int i = 0; i < 2; ++i)
            glds16(gb + (size_t)(i * 64 + srow) * K, lb + i * 4096);
    };
    auto stageB = [&](int h, int t) {
        const short* gb = Bbase + (size_t)(h * 128) * K + t * 64 + scol;
        short* lb = lds + (32768 + (t & 1) * 16384 + h * 8192) + stOff;
#pragma unroll
        for (int i = 0; i < 2; ++i)
            glds16(gb + (size_t)(i * 64 + srow) * K, lb + i * 4096);
    };

    auto readA = [&](int d, int rh, int fm, int ks) -> bf16x8 {
        int r7 = rh * 64 + fm * 16 + l16;
        int idx = d * 16384 + wm * 8192 + r7 * 64 + (((ks * 4 + g) ^ swz) * 8);
        return *(const bf16x8*)(lds + idx);
    };
    auto readB = [&](int d, int ch, int fn, int ks) -> bf16x8 {
        int r7 = (wn & 1) * 64 + ch * 32 + fn * 16 + l16;
        int idx = 32768 + d * 16384 + (wn >> 1) * 8192 + r7 * 64 + (((ks * 4 + g) ^ swz) * 8);
        return *(const bf16x8*)(lds + idx);
    };

    f32x4 acc[2][2][4][2];   // [rh][ch][fm][fn]
    const f32x4 fz = {0.f, 0.f, 0.f, 0.f};
#pragma unroll
    for (int a = 0; a < 2; ++a)
#pragma unroll
        for (int b = 0; b < 2; ++b)
#pragma unroll
            for (int c = 0; c < 4; ++c)
#pragma unroll
                for (int d = 0; d < 2; ++d) acc[a][b][c][d] = fz;

    bf16x8 rA[4][2], rB0[2][2], rB1[2][2];

    const int KS = K >> 6;    // 64-wide K-steps (32)
    const int J  = KS >> 1;   // iterations (16)

    // prologue: K0 fully (buf0), K1 B-halves only (its A is staged in R(W1))
    stageA(0, 0); stageA(1, 0); stageB(0, 0); stageB(1, 0);
    stageB(0, 1); stageB(1, 1);
    asm volatile("s_waitcnt vmcnt(4)" ::: "memory");   // drain K0 (leave K1-B in flight)
    __builtin_amdgcn_s_barrier();
    __builtin_amdgcn_sched_barrier(0);

    // pipeline fill: R(W1 of j=0); role-0 waves also do M(W1_0) here
    LOADA(0, 0);
    LOADB(0, 0, rB0);
    LOADB(0, 1, rB1);
    stageA(0, 1); stageA(1, 1);
    if (role == 0) { MMAQ(0, 0, rB0); MMAQ(0, 1, rB1); }   // M(W1_0)
    SYNCW();

#pragma unroll 1
    for (int j = 0; j < J; ++j) {
        const int tn0 = (2 * j + 2 < KS) ? 2 * j + 2 : KS - 1;   // clamp: last iter re-stages
        const int tn1 = (2 * j + 3 < KS) ? 2 * j + 3 : KS - 1;   // harmless duplicate data

        // ---- win A ----
        if (role) { MMAQ(0, 0, rB0); MMAQ(0, 1, rB1); }          // M(W1)
        LOADA(0, 1);
        stageB(0, tn0); stageB(1, tn0);
        if (!role) { MMAQ(1, 1, rB1); MMAQ(1, 0, rB0); }         // M(W2)
        SYNCWV();          // drains K(2j+1)-A + carried B before buf1 reads
        // ---- win B ----
        if (role) { MMAQ(1, 1, rB1); MMAQ(1, 0, rB0); }          // M(W2)
        LOADA(1, 0);
        LOADB(1, 0, rB0);
        LOADB(1, 1, rB1);
        stageA(0, tn0); stageA(1, tn0);
        if (!role) { MMAQ(0, 0, rB0); MMAQ(0, 1, rB1); }         // M(W3)
        SYNCW();
        // ---- win C ----
        if (role) { MMAQ(0, 0, rB0); MMAQ(0, 1, rB1); }          // M(W3)
        LOADA(1, 1);
        stageB(0, tn1); stageB(1, tn1);
        if (!role) { MMAQ(1, 1, rB1); MMAQ(1, 0, rB0); }         // M(W4)
        SYNCWV();          // drains K(2j+2) tiles before buf0 reads
        // ---- win D ----
        if (role) { MMAQ(1, 1, rB1); MMAQ(1, 0, rB0); }          // M(W4)
        if (j + 1 < J) {
            LOADA(0, 0);
            LOADB(0, 0, rB0);
            LOADB(0, 1, rB1);
            stageA(0, tn1); stageA(1, tn1);   // tn1 == 2(j+1)+1 when j+1 < J
            if (!role) { MMAQ(0, 0, rB0); MMAQ(0, 1, rB1); }     // M(W1 of j+1)
        }
        SYNCW();
    }

    // ---------------- epilogue: per-wave LDS transpose -> coalesced bf16x8 stores ----
    asm volatile("s_waitcnt vmcnt(0)" ::: "memory");
    __syncthreads();
    float* tb = (float*)lds + w * 1088;   // 16x68 f32 per wave (8 x 4352 B = 34 KB)
    const int r8 = lane >> 3;             // 0..7
    const int cg = (lane & 7) * 8;        // col group (8 cols)
#pragma unroll
    for (int rh = 0; rh < 2; ++rh)
#pragma unroll
        for (int fm = 0; fm < 4; ++fm) {
#pragma unroll
            for (int ch = 0; ch < 2; ++ch)
#pragma unroll
                for (int fn = 0; fn < 2; ++fn) {
                    f32x4 v = acc[rh][ch][fm][fn];
#pragma unroll
                    for (int r = 0; r < 4; ++r)
                        tb[(g * 4 + r) * 68 + ch * 32 + fn * 16 + l16] = v[r];
                }
            const int crow0 = c0 + wm * 128 + rh * 64 + fm * 16;
            const int mbase = m0 + wn * 64 + cg;
#pragma unroll
            for (int ii = 0; ii < 2; ++ii) {
                int row = ii * 8 + r8;
                bf16x8 pk;
#pragma unroll
                for (int jj = 0; jj < 8; ++jj) pk[jj] = f2bf(tb[row * 68 + cg + jj]);
                *(bf16x8*)(D + (size_t)(crow0 + row) * NN + mbase) = pk;
            }
        }
}

// ---------------- theta projections ----------------
// Wave mapping 1x4: each wave owns ALL 64 h-rows x 32 n-cols -> B-fragment scalar
// gather halved (16 ds_read_u16 per k-step per thread instead of 32).
// theta_ru: computes u (stored) and r; r*state is written directly into x0's
// state rows (fused hcx). Safe: each block writes only the (b, n0-block) region
// whose x0 reads happen earlier in this same block's k-loop.

__global__ __launch_bounds__(256, 2)
void theta_ru_kernel(const short* __restrict__ X, const short* __restrict__ ThR,
                     const short* __restrict__ ThU, const float* __restrict__ biasR,
                     const float* __restrict__ biasU, const float* __restrict__ state,
                     short* __restrict__ Uout, short* __restrict__ x0) {
    __shared__ short ldsAr[64 * 40];
    __shared__ short ldsAu[64 * 40];
    __shared__ short ldsB[32 * 136];
    const int b = blockIdx.y, n0 = blockIdx.x * 128;
    const int t = threadIdx.x, w = t >> 6, lane = t & 63;
    const int l16 = lane & 15, g = lane >> 4;
    const f32x4 fz = {0.f, 0.f, 0.f, 0.f};
    const bf16x8 bz = {0, 0, 0, 0, 0, 0, 0, 0};

    f32x4 aR[4][2], aU[4][2];   // [mi][nj]
#pragma unroll
    for (int i = 0; i < 4; i++)
#pragma unroll
        for (int j = 0; j < 2; j++) { aR[i][j] = fz; aU[i][j] = fz; }

    const int hA = t >> 2, pcA = (t & 3) * 8;

    for (int kb = 0; kb < KM; kb++) {
        for (int ks = 0; ks < 3; ks++) {
            __syncthreads();
            *(bf16x8*)(ldsAr + hA * 40 + pcA) =
                *(const bf16x8*)(ThR + ((size_t)kb * 64 + hA) * 96 + ks * 32 + pcA);
            *(bf16x8*)(ldsAu + hA * 40 + pcA) =
                *(const bf16x8*)(ThU + ((size_t)kb * 64 + hA) * 96 + ks * 32 + pcA);
#pragma unroll
            for (int i = 0; i < 2; i++) {
                int q = t + i * 256;
                int pp = q >> 4, nc = (q & 15) * 8;
                int pg = ks * 32 + pp;
                bf16x8 v = bz;
                if (pg < Pn)
                    v = *(const bf16x8*)(X + (size_t)kb * XSTRIDE + ((size_t)pg * Bb + b) * Nn_ + n0 + nc);
                *(bf16x8*)(ldsB + pp * 136 + nc) = v;
            }
            __syncthreads();
            bf16x8 ar[4], au[4];
#pragma unroll
            for (int mi = 0; mi < 4; mi++) {
                int hr = mi * 16 + l16;
                ar[mi] = *(const bf16x8*)(ldsAr + hr * 40 + g * 8);
                au[mi] = *(const bf16x8*)(ldsAu + hr * 40 + g * 8);
            }
#pragma unroll
            for (int nj = 0; nj < 2; nj++) {
                int col = w * 32 + nj * 16 + l16;
                bf16x8 bv;
#pragma unroll
                for (int j = 0; j < 8; j++) bv[j] = ldsB[(g * 8 + j) * 136 + col];
#pragma unroll
                for (int mi = 0; mi < 4; mi++) {
                    aR[mi][nj] = __builtin_amdgcn_mfma_f32_16x16x32_bf16(ar[mi], bv, aR[mi][nj], 0, 0, 0);
                    aU[mi][nj] = __builtin_amdgcn_mfma_f32_16x16x32_bf16(au[mi], bv, aU[mi][nj], 0, 0, 0);
                }
            }
        }
    }
#pragma unroll
    for (int mi = 0; mi < 4; mi++)
#pragma unroll
        for (int nj = 0; nj < 2; nj++) {
            int n = n0 + w * 32 + nj * 16 + l16;
            int h0 = mi * 16 + g * 4;
            size_t base = ((size_t)b * Nn_ + n) * Hn + h0;
            f32x4 st = *(const f32x4*)(state + base);
            s16x4 uv;
#pragma unroll
            for (int r = 0; r < 4; r++) {
                float zr = aR[mi][nj][r] + biasR[h0 + r];
                float zu = aU[mi][nj][r] + biasU[h0 + r];
                float rr = 1.f / (1.f + __expf(-zr));
                uv[r] = f2bf(1.f / (1.f + __expf(-zu)));
                x0[((size_t)(DESCn + h0 + r) * Bb + b) * Nn_ + n] = f2bf(rr * st[r]);
            }
            *(s16x4*)(Uout + base) = uv;
        }
}

__global__ __launch_bounds__(256, 2)
void theta_c_kernel(const short* __restrict__ X, const short* __restrict__ ThC,
                    const float* __restrict__ biasC, const short* __restrict__ U,
                    const float* __restrict__ state, float* __restrict__ out) {
    __shared__ short ldsA[64 * 40];
    __shared__ short ldsB[32 * 136];
    const int b = blockIdx.y, n0 = blockIdx.x * 128;
    const int t = threadIdx.x, w = t >> 6, lane = t & 63;
    const int l16 = lane & 15, g = lane >> 4;
    const f32x4 fz = {0.f, 0.f, 0.f, 0.f};
    const bf16x8 bz = {0, 0, 0, 0, 0, 0, 0, 0};

    f32x4 aC[4][2];
#pragma unroll
    for (int i = 0; i < 4; i++)
#pragma unroll
        for (int j = 0; j < 2; j++) aC[i][j] = fz;

    const int hA = t >> 2, pcA = (t & 3) * 8;

    for (int kb = 0; kb < KM; kb++) {
        for (int ks = 0; ks < 3; ks++) {
            __syncthreads();
            *(bf16x8*)(ldsA + hA * 40 + pcA) =
                *(const bf16x8*)(ThC + ((size_t)kb * 64 + hA) * 96 + ks * 32 + pcA);
#pragma unroll
            for (int i = 0; i < 2; i++) {
                int q = t + i * 256;
                int pp = q >> 4, nc = (q & 15) * 8;
                int pg = ks * 32 + pp;
                bf16x8 v = bz;
                if (pg < Pn)
                    v = *(const bf16x8*)(X + (size_t)kb * XSTRIDE + ((size_t)pg * Bb + b) * Nn_ + n0 + nc);
                *(bf16x8*)(ldsB + pp * 136 + nc) = v;
            }
            __syncthreads();
            bf16x8 ac[4];
#pragma unroll
            for (int mi = 0; mi < 4; mi++)
                ac[mi] = *(const bf16x8*)(ldsA + (mi * 16 + l16) * 40 + g * 8);
#pragma unroll
            for (int nj = 0; nj < 2; nj++) {
                int col = w * 32 + nj * 16 + l16;
                bf16x8 bv;
#pragma unroll
                for (int j = 0; j < 8; j++) bv[j] = ldsB[(g * 8 + j) * 136 + col];
#pragma unroll
                for (int mi = 0; mi < 4; mi++)
                    aC[mi][nj] = __builtin_amdgcn_mfma_f32_16x16x32_bf16(ac[mi], bv, aC[mi][nj], 0, 0, 0);
            }
        }
    }
#pragma unroll
    for (int mi = 0; mi < 4; mi++)
#pragma unroll
        for (int nj = 0; nj < 2; nj++) {
            int n = n0 + w * 32 + nj * 16 + l16;
            int h0 = mi * 16 + g * 4;
            size_t base = ((size_t)b * Nn_ + n) * Hn + h0;
            f32x4 st = *(const f32x4*)(state + base);
            s16x4 uv = *(const s16x4*)(U + base);
            f32x4 o;
#pragma unroll
            for (int r = 0; r < 4; r++) {
                float cc = tanhf(aC[mi][nj][r] + biasC[h0 + r]);
                float uu = bf2f(uv[r]);
                o[r] = uu * st[r] + (1.f - uu) * cc;
            }
            *(f32x4*)(out + base) = o;
        }
}

// ---------------- launcher ----------------

extern "C" void kernel_launch(void* const* d_in, const int* in_sizes, int n_in,
                              void* d_out, int out_size, void* d_ws, size_t ws_size,
                              hipStream_t stream) {
    (void)in_sizes; (void)n_in; (void)out_size; (void)ws_size;
    const float* inputs = (const float*)d_in[0];
    const float* state  = (const float*)d_in[1];
    const float* adj    = (const float*)d_in[2];
    const float* thR    = (const float*)d_in[3];
    const float* thU    = (const float*)d_in[4];
    const float* thC    = (const float*)d_in[5];
    const float* bR     = (const float*)d_in[6];
    const float* bU     = (const float*)d_in[7];
    const float* bC     = (const float*)d_in[8];
    float* out = (float*)d_out;

    char* p = (char*)d_ws;
    auto alloc = [&](size_t bytes) -> void* {
        void* r = (void*)p;
        p += (bytes + 255) & ~(size_t)255;
        return r;
    };
    short* S0   = (short*)alloc((size_t)Nn_ * Nn_ * 2);
    short* S1   = (short*)alloc((size_t)Nn_ * Nn_ * 2);
    short* Ssq0 = (short*)alloc((size_t)Nn_ * Nn_ * 2);
    short* Ssq1 = (short*)alloc((size_t)Nn_ * Nn_ * 2);
    float* sums = (float*)alloc(2 * Nn_ * 4);   // rsum | csum
    short* xb   = (short*)alloc(5 * XSTRIDE * 2);
    short* TR   = (short*)alloc((size_t)KM * 64 * 96 * 2);
    short* TU   = (short*)alloc((size_t)KM * 64 * 96 * 2);
    short* TC   = (short*)alloc((size_t)KM * 64 * 96 * 2);
    short* Ub   = (short*)alloc((size_t)Bb * Nn_ * Hn * 2);

    short* x0 = xb;
    short* y1 = xb + 1 * XSTRIDE;
    short* y2 = xb + 2 * XSTRIDE;
    short* y3 = xb + 3 * XSTRIDE;
    short* y4 = xb + 4 * XSTRIDE;
    short* S0T = y3;   // transient: consumed by D1 before y3 is written (D2)
    short* S1T = y4;
    const size_t HOFF = (size_t)DESCn * Bb * Nn_;   // start of state-feature rows

    hipMemsetAsync(sums, 0, 2 * Nn_ * 4, stream);
    sums_kernel<<<dim3(32, 32), 256, 0, stream>>>(adj, sums, sums + Nn_);
    build_S_kernel<<<dim3(32, 32), 256, 0, stream>>>(adj, sums, sums + Nn_, S0, S1, S0T, S1T);
    build_x0_kernel<<<dim3(32, Bb), 256, 0, stream>>>(inputs, state, x0);
    int rt_grid = (KM * 64 * 96 + 255) / 256;
    reorder_theta3_kernel<<<rt_grid, 256, 0, stream>>>(thR, thU, thC, TR, TU, TC);

    // D1 (208 blocks): Ssq0 = S0*S0, Ssq1 = S1*S1, y1 = S0 x0
    GemmJobs d1;
    d1.j[0] = { S0, S0T, Ssq0, 0 };
    d1.j[1] = { S1, S1T, Ssq1, 8 };
    d1.j[2] = { x0, S0,   y1, 16 };
    d1.j[3] = d1.j[2];
    gemm_bt_256<<<dim3(8, 26), 512, 0, stream>>>(d1, 3, Nn_, Nn_);

    // D2 (240 blocks): y3 = S1 x0, y2 = Ssq0 x0, y4 = Ssq1 x0
    GemmJobs d2;
    d2.j[0] = { x0, S1,   y3, 0 };
    d2.j[1] = { x0, Ssq0, y2, 10 };
    d2.j[2] = { x0, Ssq1, y4, 20 };
    d2.j[3] = d2.j[2];
    gemm_bt_256<<<dim3(8, 30), 512, 0, stream>>>(d2, 3, Nn_, Nn_);

    theta_ru_kernel<<<dim3(Nn_ / 128, Bb), 256, 0, stream>>>(xb, TR, TU, bR, bU, state, Ub, x0);

    // D3 (256 blocks): c-path, state-feature rows only (input rows unchanged)
    GemmJobs d3;
    d3.j[0] = { x0 + HOFF, S0,   y1 + HOFF, 0 };
    d3.j[1] = { x0 + HOFF, Ssq0, y2 + HOFF, 8 };
    d3.j[2] = { x0 + HOFF, S1,   y3 + HOFF, 16 };
    d3.j[3] = { x0 + HOFF, Ssq1, y4 + HOFF, 24 };
    gemm_bt_256<<<dim3(8, 32), 512, 0, stream>>>(d3, 4, Nn_, Nn_);

    theta_c_kernel<<<dim3(Nn_ / 128, Bb), 256, 0, stream>>>(xb, TC, bC, Ub, state, out);
}